// Round 1
// baseline (673.135 us; speedup 1.0000x reference)
//
#include <hip/hip_runtime.h>
#include <stdint.h>

// 3-layer GCN. A = sym-normalized adjacency with self loops (same all layers).
// Factorization: layer1 aggregates x (dim2); layer2 aggregates h1 (dim30),
// reusing Ax for the concat half; layer3 aggregates z2@W3 (dim1).
// CSR built per-call (histogram + scan + scatter) -> gather-only aggregation.

__global__ void k_detect(const unsigned* ei, int* flag) {
    __shared__ int nz;
    if (threadIdx.x == 0) nz = 0;
    __syncthreads();
    unsigned v = ei[2 * threadIdx.x + 1];
    if (v != 0) atomicAdd(&nz, 1);
    __syncthreads();
    if (threadIdx.x == 0) *flag = (nz == 0) ? 1 : 0;  // all-zero high words => int64
}

__global__ void k_hist(const void* ei, long long E, const int* flag, int* cnt) {
    long long e = (long long)blockIdx.x * 256 + threadIdx.x;
    if (e >= E) return;
    int d;
    if (*flag) d = (int)((const long long*)ei)[E + e];
    else       d = ((const int*)ei)[E + e];
    atomicAdd(&cnt[d], 1);
}

__global__ void k_scan_partial(const int* cnt, int* bsum, int n) {
    __shared__ int sh[256];
    int t = threadIdx.x;
    int base = blockIdx.x * 1024;
    int s = 0;
    for (int k = 0; k < 4; k++) {
        int idx = base + t + 256 * k;
        if (idx < n) s += cnt[idx];
    }
    sh[t] = s; __syncthreads();
    for (int off = 128; off > 0; off >>= 1) {
        if (t < off) sh[t] += sh[t + off];
        __syncthreads();
    }
    if (t == 0) bsum[blockIdx.x] = sh[0];
}

__global__ void k_scan_offsets(const int* bsum, int* boff, int* indptr, int nb, int n) {
    if (threadIdx.x == 0 && blockIdx.x == 0) {
        int run = 0;
        for (int i = 0; i < nb; i++) { boff[i] = run; run += bsum[i]; }
        indptr[n] = run;
    }
}

__global__ void k_scan_final(const int* cnt, const int* boff, int* indptr,
                             float* dinv, float2* p1, const float* x, int n) {
    __shared__ int sh[256];
    int t = threadIdx.x;
    int base = blockIdx.x * 1024 + t * 4;
    int v0 = 0, v1 = 0, v2 = 0, v3 = 0;
    if (base + 3 < n) {
        int4 c = *(const int4*)(cnt + base);
        v0 = c.x; v1 = c.y; v2 = c.z; v3 = c.w;
    } else {
        if (base + 0 < n) v0 = cnt[base + 0];
        if (base + 1 < n) v1 = cnt[base + 1];
        if (base + 2 < n) v2 = cnt[base + 2];
        if (base + 3 < n) v3 = cnt[base + 3];
    }
    int tot = v0 + v1 + v2 + v3;
    sh[t] = tot; __syncthreads();
    for (int off = 1; off < 256; off <<= 1) {
        int add = (t >= off) ? sh[t - off] : 0;
        __syncthreads();
        sh[t] += add;
        __syncthreads();
    }
    int runp = boff[blockIdx.x] + sh[t] - tot;  // exclusive prefix
    int vv[4] = {v0, v1, v2, v3};
    for (int i = 0; i < 4; i++) {
        int idx = base + i;
        if (idx < n) {
            indptr[idx] = runp;
            float dg = (float)(vv[i] + 1);          // +1 self loop, deg>=1 always
            float r = rsqrtf(dg);
            r = r * (1.5f - 0.5f * dg * r * r);     // Newton refine for accuracy
            dinv[idx] = r;
            p1[idx] = make_float2(x[2 * idx] * r, x[2 * idx + 1] * r);
        }
        runp += vv[i];
    }
}

__global__ void k_scatter(const void* ei, long long E, const int* flag,
                          const int* indptr, int* cursor, int* csr) {
    long long e = (long long)blockIdx.x * 256 + threadIdx.x;
    if (e >= E) return;
    int s, d;
    if (*flag) {
        const long long* p = (const long long*)ei;
        s = (int)p[e]; d = (int)p[E + e];
    } else {
        const int* p = (const int*)ei;
        s = p[e]; d = p[E + e];
    }
    int pos = indptr[d] + atomicAdd(&cursor[d], 1);
    csr[pos] = s;
}

// out_v = dinv_v * (p1_v + sum_{u->v} p1_u)   (dim 2)
__global__ void k_agg2(const float2* p1, const int* indptr, const int* csr,
                       const float* dinv, float2* aggx, int n) {
    int v = blockIdx.x * 256 + threadIdx.x;
    if (v >= n) return;
    float2 a = p1[v];
    int s = indptr[v], e = indptr[v + 1];
    for (int i = s; i < e; i++) {
        float2 q = p1[csr[i]];
        a.x += q.x; a.y += q.y;
    }
    float r = dinv[v];
    aggx[v] = make_float2(a.x * r, a.y * r);
}

// h1 = relu((Ax)W1 + b1); p2 = h1 * dinv, padded stride 32
__global__ void k_layer1(const float2* aggx, const float* W1, const float* b1,
                         const float* dinv, float* p2, int n) {
    int t = blockIdx.x * 256 + threadIdx.x;
    if (t >= n * 30) return;
    int v = t / 30, j = t - v * 30;
    float2 a = aggx[v];
    float h = fmaf(a.x, W1[j], fmaf(a.y, W1[30 + j], b1[j]));
    h = fmaxf(h, 0.f);
    p2[v * 32 + j] = h * dinv[v];
}

// aggh_v = dinv_v * (p2_v + sum p2_u)  (dim 30; 32-lane group per node)
__global__ void k_agg30(const float* p2, const int* indptr, const int* csr,
                        const float* dinv, float* aggh, int n) {
    int g = blockIdx.x * 8 + (threadIdx.x >> 5);
    int j = threadIdx.x & 31;
    if (g >= n) return;
    float acc = p2[g * 32 + j];  // lanes 30/31 read padding, never stored
    int s = indptr[g], e = indptr[g + 1];
    for (int i = s; i < e; i++) {
        int u = csr[i];
        acc += p2[u * 32 + j];   // one aligned 128B segment per edge
    }
    if (j < 30) aggh[g * 32 + j] = acc * dinv[g];
}

// h2 = relu((Ah1)W2[:30] + (Ax)W2[30:] + b2); p3 = ([h2,x]@W3) * dinv
__global__ void k_layer2(const float* aggh, const float2* aggx, const float* x,
                         const float* W2, const float* W3, const float* b2,
                         const float* dinv, float* p3, int n) {
    __shared__ float W2s[32 * 30];
    __shared__ float W3s[32];
    __shared__ float b2s[30];
    int t = threadIdx.x;
    for (int i = t; i < 960; i += 256) W2s[i] = W2[i];
    if (t < 32) W3s[t] = W3[t];
    if (t < 30) b2s[t] = b2[t];
    __syncthreads();
    int v = blockIdx.x * 256 + t;
    if (v >= n) return;
    float2 a = aggx[v];
    float acc[30];
#pragma unroll
    for (int j = 0; j < 30; j++)
        acc[j] = fmaf(a.x, W2s[30 * 30 + j], fmaf(a.y, W2s[31 * 30 + j], b2s[j]));
#pragma unroll
    for (int k = 0; k < 30; k++) {
        float hv = aggh[v * 32 + k];
#pragma unroll
        for (int j = 0; j < 30; j++)
            acc[j] = fmaf(hv, W2s[k * 30 + j], acc[j]);
    }
    float s3 = 0.f;
#pragma unroll
    for (int j = 0; j < 30; j++) s3 = fmaf(fmaxf(acc[j], 0.f), W3s[j], s3);
    s3 = fmaf(x[2 * v], W3s[30], s3);
    s3 = fmaf(x[2 * v + 1], W3s[31], s3);
    p3[v] = s3 * dinv[v];
}

// out_v = dinv_v * (p3_v + sum p3_u) + b3   (dim 1)
__global__ void k_agg1(const float* p3, const int* indptr, const int* csr,
                       const float* dinv, const float* b3, float* out, int n) {
    int v = blockIdx.x * 256 + threadIdx.x;
    if (v >= n) return;
    float acc = p3[v];
    int s = indptr[v], e = indptr[v + 1];
    for (int i = s; i < e; i++) acc += p3[csr[i]];
    out[v] = fmaf(acc, dinv[v], b3[0]);
}

extern "C" void kernel_launch(void* const* d_in, const int* in_sizes, int n_in,
                              void* d_out, int out_size, void* d_ws, size_t ws_size,
                              hipStream_t stream) {
    const float* x  = (const float*)d_in[0];
    const void*  ei = d_in[1];
    const float* W1 = (const float*)d_in[2];
    const float* b1 = (const float*)d_in[3];
    const float* W2 = (const float*)d_in[4];
    const float* b2 = (const float*)d_in[5];
    const float* W3 = (const float*)d_in[6];
    const float* b3 = (const float*)d_in[7];
    float* out = (float*)d_out;
    const int n = in_sizes[0] / 2;
    const long long E = in_sizes[1] / 2;

    char* w = (char*)d_ws;
    auto alloc = [&](size_t b) { void* p = (void*)w; w += (b + 255) & ~(size_t)255; return p; };
    int*    flag   = (int*)alloc(4);
    int*    cnt    = (int*)alloc((size_t)n * 4);
    int*    indptr = (int*)alloc(((size_t)n + 1) * 4);
    int*    cursor = (int*)alloc((size_t)n * 4);
    float*  dinv   = (float*)alloc((size_t)n * 4);
    int*    csr    = (int*)alloc((size_t)E * 4);
    float2* p1     = (float2*)alloc((size_t)n * 8);
    float2* aggx   = (float2*)alloc((size_t)n * 8);
    float*  p2     = (float*)alloc((size_t)n * 32 * 4);
    float*  aggh   = (float*)alloc((size_t)n * 32 * 4);
    float*  p3     = (float*)alloc((size_t)n * 4);
    int*    bsum   = (int*)alloc(4096);
    int*    boff   = (int*)alloc(4096);

    hipMemsetAsync(cnt, 0, (size_t)n * 4, stream);
    hipMemsetAsync(cursor, 0, (size_t)n * 4, stream);

    int eblocks = (int)((E + 255) / 256);
    int nb = (n + 1023) / 1024;
    int nblocks = (n + 255) / 256;

    k_detect<<<1, 256, 0, stream>>>((const unsigned*)ei, flag);
    k_hist<<<eblocks, 256, 0, stream>>>(ei, E, flag, cnt);
    k_scan_partial<<<nb, 256, 0, stream>>>(cnt, bsum, n);
    k_scan_offsets<<<1, 1, 0, stream>>>(bsum, boff, indptr, nb, n);
    k_scan_final<<<nb, 256, 0, stream>>>(cnt, boff, indptr, dinv, p1, x, n);
    k_scatter<<<eblocks, 256, 0, stream>>>(ei, E, flag, indptr, cursor, csr);
    k_agg2<<<nblocks, 256, 0, stream>>>(p1, indptr, csr, dinv, aggx, n);
    k_layer1<<<(n * 30 + 255) / 256, 256, 0, stream>>>(aggx, W1, b1, dinv, p2, n);
    k_agg30<<<(n + 7) / 8, 256, 0, stream>>>(p2, indptr, csr, dinv, aggh, n);
    k_layer2<<<nblocks, 256, 0, stream>>>(aggh, aggx, x, W2, W3, b2, dinv, p3, n);
    k_agg1<<<nblocks, 256, 0, stream>>>(p3, indptr, csr, dinv, b3, out, n);
}

// Round 2
// 403.177 us; speedup vs baseline: 1.6696x; 1.6696x over previous
//
#include <hip/hip_runtime.h>
#include <stdint.h>

// 3-layer GCN, gather-only aggregation off a per-node CSR.
// CSR build = two-level counting sort with DETERMINISTIC offsets (no global
// atomics): (1) bin edges into buckets of 256 dst-nodes via per-block LDS
// histograms + (bucket x block) offset matrix; (2) per-bucket LDS counting
// sort to node granularity. Packed edge = (src<<8)|(dst&255), src<2^18.

#define NB 256  // binning blocks

__global__ void k_detect(const unsigned* ei, int* flag) {
    __shared__ int nz;
    if (threadIdx.x == 0) nz = 0;
    __syncthreads();
    unsigned v = ei[2 * threadIdx.x + 1];
    if (v != 0) atomicAdd(&nz, 1);
    __syncthreads();
    if (threadIdx.x == 0) *flag = (nz == 0) ? 1 : 0;  // all-zero high words => int64
}

// Pass A: per-block bucket histogram -> block_cnt[bucket*NB + blk]
__global__ void k_binA(const void* ei, long long E, const int* flag,
                       int* block_cnt, int B) {
    extern __shared__ int hist[];
    int t = threadIdx.x, blk = blockIdx.x;
    for (int i = t; i < B; i += 256) hist[i] = 0;
    __syncthreads();
    int f = *flag;
    long long chunk = (E + NB - 1) / NB;
    long long s = (long long)blk * chunk, e = min(E, s + chunk);
    if (f) {
        const long long* p = (const long long*)ei;
        for (long long i = s + t; i < e; i += 256)
            atomicAdd(&hist[((int)p[E + i]) >> 8], 1);
    } else {
        const int* p = (const int*)ei;
        for (long long i = s + t; i < e; i += 256)
            atomicAdd(&hist[p[E + i] >> 8], 1);
    }
    __syncthreads();
    for (int i = t; i < B; i += 256) block_cnt[i * NB + blk] = hist[i];
}

// Per-bucket exclusive scan over blocks (in place); bucket totals out.
__global__ void k_colsum(int* block_cnt, int* bucket_cnt) {
    __shared__ int sh[NB];
    int t = threadIdx.x, b = blockIdx.x;
    int v = block_cnt[b * NB + t];
    sh[t] = v;
    __syncthreads();
    for (int off = 1; off < NB; off <<= 1) {
        int add = (t >= off) ? sh[t - off] : 0;
        __syncthreads();
        sh[t] += add;
        __syncthreads();
    }
    block_cnt[b * NB + t] = sh[t] - v;  // exclusive prefix within bucket
    if (t == NB - 1) bucket_cnt[b] = sh[t];
}

// Exclusive scan over buckets -> bucket_base[0..B], also indptr[n]=E.
__global__ void k_bucketscan(const int* bucket_cnt, int* bucket_base, int B,
                             long long E, int* indptr, int n) {
    __shared__ int sh[256];
    int t = threadIdx.x;
    int i0 = t * 4;
    int v[4];
    int tot = 0;
    for (int k = 0; k < 4; k++) {
        v[k] = (i0 + k < B) ? bucket_cnt[i0 + k] : 0;
        tot += v[k];
    }
    sh[t] = tot;
    __syncthreads();
    for (int off = 1; off < 256; off <<= 1) {
        int add = (t >= off) ? sh[t - off] : 0;
        __syncthreads();
        sh[t] += add;
        __syncthreads();
    }
    int run = sh[t] - tot;
    for (int k = 0; k < 4; k++) {
        if (i0 + k < B) bucket_base[i0 + k] = run;
        run += v[k];
    }
    if (t == 0) { bucket_base[B] = (int)E; indptr[n] = (int)E; }
}

// Pass B: write packed edges to deterministic bucket slots.
__global__ void k_binB(const void* ei, long long E, const int* flag,
                       const int* block_cnt, const int* bucket_base,
                       unsigned* binned, int B) {
    extern __shared__ int cur[];
    int t = threadIdx.x, blk = blockIdx.x;
    for (int i = t; i < B; i += 256)
        cur[i] = bucket_base[i] + block_cnt[i * NB + blk];
    __syncthreads();
    int f = *flag;
    long long chunk = (E + NB - 1) / NB;
    long long s = (long long)blk * chunk, e = min(E, s + chunk);
    if (f) {
        const long long* p = (const long long*)ei;
        for (long long i = s + t; i < e; i += 256) {
            int sv = (int)p[i], dv = (int)p[E + i];
            int slot = atomicAdd(&cur[dv >> 8], 1);
            binned[slot] = ((unsigned)sv << 8) | (unsigned)(dv & 255);
        }
    } else {
        const int* p = (const int*)ei;
        for (long long i = s + t; i < e; i += 256) {
            int sv = p[i], dv = p[E + i];
            int slot = atomicAdd(&cur[dv >> 8], 1);
            binned[slot] = ((unsigned)sv << 8) | (unsigned)(dv & 255);
        }
    }
}

// Per-bucket counting sort -> csr; also indptr, dinv, p1 = x*dinv.
__global__ void k_bucket_csr(const unsigned* binned, const int* bucket_base,
                             const float* x, int* indptr, float* dinv,
                             float2* p1, int* csr, int n) {
    __shared__ int hist[256], excl[256], cursor[256];
    int t = threadIdx.x, b = blockIdx.x;
    int base = bucket_base[b], end = bucket_base[b + 1];
    hist[t] = 0;
    __syncthreads();
    for (int i = base + t; i < end; i += 256)
        atomicAdd(&hist[binned[i] & 255u], 1);
    __syncthreads();
    int v = hist[t];
    excl[t] = v;
    __syncthreads();
    // inclusive scan into excl
    for (int off = 1; off < 256; off <<= 1) {
        int add = (t >= off) ? excl[t - off] : 0;
        __syncthreads();
        excl[t] += add;
        __syncthreads();
    }
    int ex = excl[t] - v;  // exclusive
    int node = b * 256 + t;
    if (node < n) {
        indptr[node] = base + ex;
        float dg = (float)(v + 1);
        float r = rsqrtf(dg);
        r = r * (1.5f - 0.5f * dg * r * r);
        dinv[node] = r;
        p1[node] = make_float2(x[2 * node] * r, x[2 * node + 1] * r);
    }
    cursor[t] = base + ex;
    __syncthreads();
    for (int i = base + t; i < end; i += 256) {
        unsigned p = binned[i];
        int slot = atomicAdd(&cursor[p & 255u], 1);
        csr[slot] = (int)(p >> 8);
    }
}

// Fused: aggx = A_hat x (dim2); p2 = relu(aggx@W1+b1)*dinv, stride 32.
__global__ void k_agg2_l1(const float2* p1, const int* indptr, const int* csr,
                          const float* dinv, const float* W1, const float* b1,
                          float2* aggx, float* p2, int n) {
    int v = blockIdx.x * 256 + threadIdx.x;
    if (v >= n) return;
    float2 a = p1[v];
    int s = indptr[v], e = indptr[v + 1];
    for (int i = s; i < e; i++) {
        float2 q = p1[csr[i]];
        a.x += q.x; a.y += q.y;
    }
    float r = dinv[v];
    float ax = a.x * r, ay = a.y * r;
    aggx[v] = make_float2(ax, ay);
    float4 o[8];
    float* of = (float*)o;
#pragma unroll
    for (int j = 0; j < 30; j++)
        of[j] = fmaxf(fmaf(ax, W1[j], fmaf(ay, W1[30 + j], b1[j])), 0.f) * r;
    of[30] = 0.f; of[31] = 0.f;
    float4* d4 = (float4*)(p2 + (size_t)v * 32);
#pragma unroll
    for (int k = 0; k < 8; k++) d4[k] = o[k];
}

// aggh_v = dinv_v * (p2_v + sum p2_u)  (dim 30; 32-lane group per node)
__global__ void k_agg30(const float* p2, const int* indptr, const int* csr,
                        const float* dinv, float* aggh, int n) {
    int g = blockIdx.x * 8 + (threadIdx.x >> 5);
    int j = threadIdx.x & 31;
    if (g >= n) return;
    float acc = p2[(size_t)g * 32 + j];  // lanes 30/31 read zero padding
    int s = indptr[g], e = indptr[g + 1];
    for (int i = s; i < e; i++) {
        int u = csr[i];
        acc += p2[(size_t)u * 32 + j];  // one aligned 128B segment per edge
    }
    if (j < 30) aggh[(size_t)g * 32 + j] = acc * dinv[g];
}

// h2 = relu((Ah1)W2[:30] + (Ax)W2[30:] + b2); p3 = ([h2,x]@W3) * dinv
__global__ void k_layer2(const float* aggh, const float2* aggx, const float* x,
                         const float* W2, const float* W3, const float* b2,
                         const float* dinv, float* p3, int n) {
    __shared__ float W2s[32 * 30];
    __shared__ float W3s[32];
    __shared__ float b2s[30];
    int t = threadIdx.x;
    for (int i = t; i < 960; i += 256) W2s[i] = W2[i];
    if (t < 32) W3s[t] = W3[t];
    if (t < 30) b2s[t] = b2[t];
    __syncthreads();
    int v = blockIdx.x * 256 + t;
    if (v >= n) return;
    float2 a = aggx[v];
    float acc[30];
#pragma unroll
    for (int j = 0; j < 30; j++)
        acc[j] = fmaf(a.x, W2s[30 * 30 + j], fmaf(a.y, W2s[31 * 30 + j], b2s[j]));
#pragma unroll
    for (int k = 0; k < 30; k++) {
        float hv = aggh[(size_t)v * 32 + k];
#pragma unroll
        for (int j = 0; j < 30; j++)
            acc[j] = fmaf(hv, W2s[k * 30 + j], acc[j]);
    }
    float s3 = 0.f;
#pragma unroll
    for (int j = 0; j < 30; j++) s3 = fmaf(fmaxf(acc[j], 0.f), W3s[j], s3);
    s3 = fmaf(x[2 * v], W3s[30], s3);
    s3 = fmaf(x[2 * v + 1], W3s[31], s3);
    p3[v] = s3 * dinv[v];
}

// out_v = dinv_v * (p3_v + sum p3_u) + b3   (dim 1)
__global__ void k_agg1(const float* p3, const int* indptr, const int* csr,
                       const float* dinv, const float* b3, float* out, int n) {
    int v = blockIdx.x * 256 + threadIdx.x;
    if (v >= n) return;
    float acc = p3[v];
    int s = indptr[v], e = indptr[v + 1];
    for (int i = s; i < e; i++) acc += p3[csr[i]];
    out[v] = fmaf(acc, dinv[v], b3[0]);
}

extern "C" void kernel_launch(void* const* d_in, const int* in_sizes, int n_in,
                              void* d_out, int out_size, void* d_ws, size_t ws_size,
                              hipStream_t stream) {
    const float* x  = (const float*)d_in[0];
    const void*  ei = d_in[1];
    const float* W1 = (const float*)d_in[2];
    const float* b1 = (const float*)d_in[3];
    const float* W2 = (const float*)d_in[4];
    const float* b2 = (const float*)d_in[5];
    const float* W3 = (const float*)d_in[6];
    const float* b3 = (const float*)d_in[7];
    float* out = (float*)d_out;
    const int n = in_sizes[0] / 2;
    const long long E = in_sizes[1] / 2;
    const int B = (n + 255) / 256;  // dst buckets of 256 nodes

    char* w = (char*)d_ws;
    auto alloc = [&](size_t b) { void* p = (void*)w; w += (b + 255) & ~(size_t)255; return p; };
    int*      flag        = (int*)alloc(4);
    int*      block_cnt   = (int*)alloc((size_t)B * NB * 4);
    int*      bucket_cnt  = (int*)alloc((size_t)B * 4);
    int*      bucket_base = (int*)alloc(((size_t)B + 1) * 4);
    unsigned* binned      = (unsigned*)alloc((size_t)E * 4);
    int*      indptr      = (int*)alloc(((size_t)n + 1) * 4);
    float*    dinv        = (float*)alloc((size_t)n * 4);
    int*      csr         = (int*)alloc((size_t)E * 4);
    float2*   p1          = (float2*)alloc((size_t)n * 8);
    float2*   aggx        = (float2*)alloc((size_t)n * 8);
    float*    p2          = (float*)alloc((size_t)n * 32 * 4);
    float*    aggh        = (float*)alloc((size_t)n * 32 * 4);
    float*    p3          = (float*)alloc((size_t)n * 4);

    int nblocks = (n + 255) / 256;
    size_t lds = (size_t)B * 4;

    k_detect<<<1, 256, 0, stream>>>((const unsigned*)ei, flag);
    k_binA<<<NB, 256, lds, stream>>>(ei, E, flag, block_cnt, B);
    k_colsum<<<B, NB, 0, stream>>>(block_cnt, bucket_cnt);
    k_bucketscan<<<1, 256, 0, stream>>>(bucket_cnt, bucket_base, B, E, indptr, n);
    k_binB<<<NB, 256, lds, stream>>>(ei, E, flag, block_cnt, bucket_base, binned, B);
    k_bucket_csr<<<B, 256, 0, stream>>>(binned, bucket_base, x, indptr, dinv, p1, csr, n);
    k_agg2_l1<<<nblocks, 256, 0, stream>>>(p1, indptr, csr, dinv, W1, b1, aggx, p2, n);
    k_agg30<<<(n + 7) / 8, 256, 0, stream>>>(p2, indptr, csr, dinv, aggh, n);
    k_layer2<<<nblocks, 256, 0, stream>>>(aggh, aggx, x, W2, W3, b2, dinv, p3, n);
    k_agg1<<<nblocks, 256, 0, stream>>>(p3, indptr, csr, dinv, b3, out, n);
}